// Round 2
// baseline (705.504 us; speedup 1.0000x reference)
//
#include <hip/hip_runtime.h>

// ---------------- problem constants ----------------
#define B_    4
#define CI_   2
#define H_    48
#define W_    48
#define T_    96
#define CO_   64
#define XO_   23
#define NSITE 529         // 23*23
#define TP_   145         // output time steps (29*5 exactly)
#define TPAD_ 224         // padded LDS time window per row
#define NTAP_ 18          // CI*3*3
#define THETA_ 5.4f
#define FODEP_ 48
#define WCAP_  265        // ceil(0.5*529)

// ws layout (floats)
#define WS_WKF 0                      // [64][18][48] = 55296 floats
#define WS_KS  55296                  // [64][18] ints = 1152
#define WS_M   (55296 + 1152)         // [4][145][529] floats = 306820
#define WS_A   (WS_M + 306820)        // [4][145][529] ints

// ---------------- kernel: zero output ----------------
__global__ void k_zero(float4* __restrict__ p, int n4) {
    int stride = gridDim.x * blockDim.x;
    for (int i = blockIdx.x * blockDim.x + threadIdx.x; i < n4; i += stride)
        p[i] = make_float4(0.f, 0.f, 0.f, 0.f);
}

// ---------------- kernel: temporal kernel synthesis + start-index table ----
// wkf[o][tap][kt] = kern(47-kt; w) ; kern(j;w)=max(0,min(j/16, 1.5w - j/32))
// kstab[o][tap] = first nonzero kt rounded down to multiple of 5 (48 if all zero)
__global__ void k_wk(const float* __restrict__ weight, float* __restrict__ wkf,
                     int* __restrict__ kstab) {
    int idx = blockIdx.x * 256 + threadIdx.x;       // (o, tap)
    if (idx >= CO_ * NTAP_) return;
    int o = idx / NTAP_, tap = idx % NTAP_;
    int i = tap / 9, kx = (tap % 9) / 3, ky = tap % 3;
    float w = weight[((o * CI_ + i) * 3 + kx) * 3 + ky];
    int ktlo = 48;
    for (int kt = 0; kt < 48; ++kt) {
        float j = (float)(47 - kt);
        float v = fmaxf(0.0f, fminf(j * (1.0f / 16.0f), 1.5f * w - j * (1.0f / 32.0f)));
        wkf[idx * 48 + kt] = v;
        if (v > 0.0f && ktlo == 48) ktlo = kt;
    }
    int ks = (ktlo >= 48) ? 48 : (ktlo - ktlo % 5);
    if (ks > 45 && ks < 48) ks = 45;
    kstab[idx] = ks;
}

// ---------------- kernel: conv + channel max/argmax ----------------
// block = (b, x, ychunk of 2). 256 threads = 4 waves.
// wave wq owns channels [16wq,16wq+16); lane = 2y * 32 t-groups (t_tile=5).
__launch_bounds__(256, 3)
__global__ void k_conv(const float* __restrict__ in, const float* __restrict__ wkf,
                       const int* __restrict__ kstab, const float* __restrict__ bias,
                       float* __restrict__ m_out, int* __restrict__ a_out) {
    __shared__ __align__(16) float sp[30][TPAD_];   // 26880 B
    __shared__ float red_m[4][64][5];               // 5120 B
    __shared__ int   red_a[4][64][5];               // 5120 B

    int bid = blockIdx.x;
    int b  = bid / (XO_ * 12);
    int r  = bid % (XO_ * 12);
    int x  = r / 12;
    int y0 = (r % 12) * 2;
    int tid  = threadIdx.x;
    int lane = tid & 63;
    int wq   = tid >> 6;
    int dy   = lane >> 5;          // 0/1
    int tg   = lane & 31;          // t-group
    int t0   = tg * 5;
    int y    = y0 + dy;
    bool valid = (y < XO_) && (tg < 29);

    // stage input: zero pad then fill rows. row = (i*3+kx)*5 + c, col = 2*y0+c
    for (int q = tid; q < 30 * TPAD_; q += 256) ((float*)sp)[q] = 0.0f;
    __syncthreads();
    for (int q = tid; q < 30 * 24; q += 256) {
        int row = q / 24, f4 = q % 24;
        int c = row % 5, rr = row / 5;
        int kx = rr % 3, i = rr / 3;
        int col = 2 * y0 + c;
        if (col < W_) {
            const float4* src = (const float4*)(in +
                ((((size_t)b * CI_ + i) * H_ + (2 * x + kx)) * W_ + col) * T_);
            *(float4*)(&sp[row][48 + f4 * 4]) = src[f4];
        }
    }
    __syncthreads();

    float mbest[5];
    int   abest[5];
#pragma unroll
    for (int j = 0; j < 5; ++j) { mbest[j] = -1e30f; abest[j] = 0; }

    int obase = __builtin_amdgcn_readfirstlane(wq * 16);

#pragma unroll 1
    for (int oi = 0; oi < 16; ++oi) {
        int o = obase + oi;
        float a0 = 0.f, a1 = 0.f, a2 = 0.f, a3 = 0.f, a4 = 0.f;
#pragma unroll 1
        for (int tap = 0; tap < NTAP_; ++tap) {
            int ks = __builtin_amdgcn_readfirstlane(kstab[o * NTAP_ + tap]);
            if (ks >= 48) continue;                  // whole kernel exactly zero
            int i = tap / 9, kx = (tap % 9) / 3, ky = tap % 3;
            const float* srow = sp[(i * 3 + kx) * 5 + 2 * dy + ky];
            const float* sptr = srow + t0 + ks;
            const float* wrow = wkf + (o * NTAP_ + tap) * 48;
            // rolling 5-register window, 5-phase rotation (no moves)
            float w0 = sptr[0], w1 = sptr[1], w2 = sptr[2], w3 = sptr[3], w4 = sptr[4];
            int kt = ks;
#pragma unroll 1
            for (; kt < 45; kt += 5) {
                float k0 = wrow[kt], k1 = wrow[kt + 1], k2 = wrow[kt + 2],
                      k3 = wrow[kt + 3], k4 = wrow[kt + 4];
                a0 = fmaf(k0, w0, a0); a1 = fmaf(k0, w1, a1); a2 = fmaf(k0, w2, a2);
                a3 = fmaf(k0, w3, a3); a4 = fmaf(k0, w4, a4); w0 = sptr[5];
                a0 = fmaf(k1, w1, a0); a1 = fmaf(k1, w2, a1); a2 = fmaf(k1, w3, a2);
                a3 = fmaf(k1, w4, a3); a4 = fmaf(k1, w0, a4); w1 = sptr[6];
                a0 = fmaf(k2, w2, a0); a1 = fmaf(k2, w3, a1); a2 = fmaf(k2, w4, a2);
                a3 = fmaf(k2, w0, a3); a4 = fmaf(k2, w1, a4); w2 = sptr[7];
                a0 = fmaf(k3, w3, a0); a1 = fmaf(k3, w4, a1); a2 = fmaf(k3, w0, a2);
                a3 = fmaf(k3, w1, a3); a4 = fmaf(k3, w2, a4); w3 = sptr[8];
                a0 = fmaf(k4, w4, a0); a1 = fmaf(k4, w0, a1); a2 = fmaf(k4, w1, a2);
                a3 = fmaf(k4, w2, a3); a4 = fmaf(k4, w3, a4); w4 = sptr[9];
                sptr += 5;
            }
            // tail kt = 45, 46 (K[47] == kern(0) == 0 always). window = s[t0+45..49]
            float k45 = wrow[45], k46 = wrow[46];
            a0 = fmaf(k45, w0, a0); a1 = fmaf(k45, w1, a1); a2 = fmaf(k45, w2, a2);
            a3 = fmaf(k45, w3, a3); a4 = fmaf(k45, w4, a4);
            float w5 = sptr[5];
            a0 = fmaf(k46, w1, a0); a1 = fmaf(k46, w2, a1); a2 = fmaf(k46, w3, a2);
            a3 = fmaf(k46, w4, a3); a4 = fmaf(k46, w5, a4);
        }
        // incremental max/argmax (strict > keeps smallest o on ties, o ascending)
        float bo = bias[o];
        float p0 = a0 + bo, p1 = a1 + bo, p2 = a2 + bo, p3 = a3 + bo, p4 = a4 + bo;
        if (p0 > mbest[0]) { mbest[0] = p0; abest[0] = o; }
        if (p1 > mbest[1]) { mbest[1] = p1; abest[1] = o; }
        if (p2 > mbest[2]) { mbest[2] = p2; abest[2] = o; }
        if (p3 > mbest[3]) { mbest[3] = p3; abest[3] = o; }
        if (p4 > mbest[4]) { mbest[4] = p4; abest[4] = o; }
    }

    // combine the 4 waves' o-subsets (wave order = ascending o)
#pragma unroll
    for (int j = 0; j < 5; ++j) { red_m[wq][lane][j] = mbest[j]; red_a[wq][lane][j] = abest[j]; }
    __syncthreads();
    if (wq == 0 && valid) {
        int site = x * XO_ + y;
#pragma unroll
        for (int j = 0; j < 5; ++j) {
            float mv = red_m[0][lane][j];
            int   av = red_a[0][lane][j];
#pragma unroll
            for (int w = 1; w < 4; ++w) {
                float m2 = red_m[w][lane][j];
                if (m2 > mv) { mv = m2; av = red_a[w][lane][j]; }
            }
            size_t off = ((size_t)b * TP_ + (t0 + j)) * NSITE + site;
            m_out[off] = mv;
            a_out[off] = av;
        }
    }
}

// ---------------- kernel: sequential WTA, 1 wave per batch ----------------
#define WTA_STEP(CM, CA, NM, NA, TT)                                           \
    {                                                                          \
        int c = 0;                                                             \
        _Pragma("unroll") for (int k = 0; k < 9; ++k) c += (dep[k] != 0);      \
        for (int off = 32; off > 0; off >>= 1) c += __shfl_xor(c, off);        \
        bool kok = (c < WCAP_);                                                \
        if ((TT) + 1 < TP_) {                                                  \
            const float* mr = mb + ((TT) + 1) * NSITE;                         \
            const int*   ar = ab + ((TT) + 1) * NSITE;                         \
            _Pragma("unroll") for (int k = 0; k < 9; ++k) {                    \
                int s = lane + 64 * k;                                         \
                if (s < NSITE) { NM[k] = mr[s]; NA[k] = ar[s]; }               \
            }                                                                  \
        }                                                                      \
        _Pragma("unroll") for (int k = 0; k < 9; ++k) {                        \
            int s = lane + 64 * k;                                             \
            if (s < NSITE) {                                                   \
                if (kok && dep[k] == 0 && CM[k] > THETA_) {                    \
                    out[(((size_t)b * CO_ + CA[k]) * NSITE + s) * TP_ + (TT)] = 1.0f; \
                    dep[k] = FODEP_ - 1;                                       \
                } else {                                                       \
                    dep[k] = (dep[k] > 0) ? dep[k] - 1 : 0;                    \
                }                                                              \
            }                                                                  \
        }                                                                      \
    }

__global__ void k_wta(const float* __restrict__ m_in, const int* __restrict__ a_in,
                      float* __restrict__ out) {
    int b = blockIdx.x;
    int lane = threadIdx.x;                         // 64 threads = 1 wave
    const float* mb = m_in + (size_t)b * TP_ * NSITE;
    const int*   ab = a_in + (size_t)b * TP_ * NSITE;
    int dep[9];
#pragma unroll
    for (int k = 0; k < 9; ++k) dep[k] = 0;
    float mvA[9], mvB[9];
    int   avA[9], avB[9];
#pragma unroll
    for (int k = 0; k < 9; ++k) {
        int s = lane + 64 * k;
        if (s < NSITE) { mvA[k] = mb[s]; avA[k] = ab[s]; }
    }
    for (int t = 0; t < TP_; t += 2) {
        WTA_STEP(mvA, avA, mvB, avB, t);
        if (t + 1 < TP_) WTA_STEP(mvB, avB, mvA, avA, t + 1);
    }
}

// ---------------- launcher ----------------
extern "C" void kernel_launch(void* const* d_in, const int* in_sizes, int n_in,
                              void* d_out, int out_size, void* d_ws, size_t ws_size,
                              hipStream_t stream) {
    const float* in     = (const float*)d_in[0];
    const float* weight = (const float*)d_in[1];
    const float* bias   = (const float*)d_in[2];
    float* out = (float*)d_out;

    float* wkf   = (float*)d_ws + WS_WKF;
    int*   kstab = (int*)((float*)d_ws + WS_KS);
    float* m     = (float*)d_ws + WS_M;
    int*   a     = (int*)((float*)d_ws + WS_A);

    // zero spike output: 4*64*529*145 floats
    k_zero<<<2048, 256, 0, stream>>>((float4*)out, 19636480 / 4);
    k_wk<<<(CO_ * NTAP_ + 255) / 256, 256, 0, stream>>>(weight, wkf, kstab);
    k_conv<<<B_ * XO_ * 12, 256, 0, stream>>>(in, wkf, kstab, bias, m, a);
    k_wta<<<B_, 64, 0, stream>>>(m, a, out);
}

// Round 3
// 449.751 us; speedup vs baseline: 1.5687x; 1.5687x over previous
//
#include <hip/hip_runtime.h>

// ---------------- problem constants ----------------
#define B_    4
#define CI_   2
#define H_    48
#define W_    48
#define T_    96
#define CO_   64
#define XO_   23
#define NSITE 529         // 23*23
#define TP_   145         // output time steps (29*5)
#define TPAD_ 192         // padded LDS time window per row (max read idx 190)
#define NTAP_ 18          // CI*3*3
#define THETA_ 5.4f
#define FODEP_ 48
#define WCAP_  265        // ceil(0.5*529)

// ws layout (floats)
#define WS_WKF 0                      // [64][18][48] = 55296 floats
#define WS_KS  55296                  // [64][18] ints
#define WS_M   (55296 + 1152)         // [4][145][529] floats
#define WS_A   (WS_M + 306820)        // [4][145][529] ints

// ---------------- kernel: zero output ----------------
__global__ void k_zero(float4* __restrict__ p, int n4) {
    int stride = gridDim.x * blockDim.x;
    for (int i = blockIdx.x * blockDim.x + threadIdx.x; i < n4; i += stride)
        p[i] = make_float4(0.f, 0.f, 0.f, 0.f);
}

// ---------------- kernel: temporal kernel synthesis + start-index table ----
__global__ void k_wk(const float* __restrict__ weight, float* __restrict__ wkf,
                     int* __restrict__ kstab) {
    int idx = blockIdx.x * 256 + threadIdx.x;       // (o, tap)
    if (idx >= CO_ * NTAP_) return;
    int o = idx / NTAP_, tap = idx % NTAP_;
    int i = tap / 9, kx = (tap % 9) / 3, ky = tap % 3;
    float w = weight[((o * CI_ + i) * 3 + kx) * 3 + ky];
    int ktlo = 48;
    for (int kt = 0; kt < 48; ++kt) {
        float j = (float)(47 - kt);
        float v = fmaxf(0.0f, fminf(j * (1.0f / 16.0f), 1.5f * w - j * (1.0f / 32.0f)));
        wkf[idx * 48 + kt] = v;
        if (v > 0.0f && ktlo == 48) ktlo = kt;
    }
    int ks = (ktlo >= 48) ? 48 : (ktlo - ktlo % 5);
    kstab[idx] = ks;
}

// 5-step segment of the temporal FIR, 5-phase rotating register window.
// invariant at entry: w_j == s[t0 + S + j]; at exit: w_j == s[t0 + S + 5 + j]
#define SEG(S) \
    { float k0 = wrow[(S)+0], k1 = wrow[(S)+1], k2 = wrow[(S)+2], \
            k3 = wrow[(S)+3], k4 = wrow[(S)+4]; \
      a0 = fmaf(k0, w0, a0); a1 = fmaf(k0, w1, a1); a2 = fmaf(k0, w2, a2); \
      a3 = fmaf(k0, w3, a3); a4 = fmaf(k0, w4, a4); w0 = sptr[(S)+5]; \
      a0 = fmaf(k1, w1, a0); a1 = fmaf(k1, w2, a1); a2 = fmaf(k1, w3, a2); \
      a3 = fmaf(k1, w4, a3); a4 = fmaf(k1, w0, a4); w1 = sptr[(S)+6]; \
      a0 = fmaf(k2, w2, a0); a1 = fmaf(k2, w3, a1); a2 = fmaf(k2, w4, a2); \
      a3 = fmaf(k2, w0, a3); a4 = fmaf(k2, w1, a4); w2 = sptr[(S)+7]; \
      a0 = fmaf(k3, w3, a0); a1 = fmaf(k3, w4, a1); a2 = fmaf(k3, w0, a2); \
      a3 = fmaf(k3, w1, a3); a4 = fmaf(k3, w2, a4); w3 = sptr[(S)+8]; \
      a0 = fmaf(k4, w4, a0); a1 = fmaf(k4, w0, a1); a2 = fmaf(k4, w1, a2); \
      a3 = fmaf(k4, w2, a3); a4 = fmaf(k4, w3, a4); w4 = sptr[(S)+9]; }

#define CASE(S, L) case S: w0 = sptr[(S)]; w1 = sptr[(S)+1]; w2 = sptr[(S)+2]; \
                           w3 = sptr[(S)+3]; w4 = sptr[(S)+4]; goto L;

// ---------------- kernel: conv + channel max/argmax ----------------
// block = (b, x, ychunk of 2). 4 waves; wave wq owns channels [16wq,16wq+16).
// lane = dy(2) x tg(32, t_tile=5). LDS input tile unioned with reduce bufs.
__launch_bounds__(256, 5)
__global__ void k_conv(const float* __restrict__ in, const float* __restrict__ wkf,
                       const int* __restrict__ kstab, const float* __restrict__ bias,
                       float* __restrict__ m_out, int* __restrict__ a_out) {
    __shared__ __align__(16) union {
        float sp[30][TPAD_];                        // 23040 B
        struct { float m[4][64][5]; int a[4][64][5]; } red;   // 10240 B
    } u;

    int bid = blockIdx.x;
    int b  = bid / (XO_ * 12);
    int r  = bid % (XO_ * 12);
    int x  = r / 12;
    int y0 = (r % 12) * 2;
    int tid  = threadIdx.x;
    int lane = tid & 63;
    int wq   = tid >> 6;
    int dy   = lane >> 5;                 // 0/1
    int tg   = lane & 31;                 // t-group
    int t0   = (tg < 29) ? tg * 5 : 140;  // clamp garbage lanes in-bounds
    int y    = y0 + dy;
    bool valid = (y < XO_) && (tg < 29);

    // zero pad (float4) then fill rows. row = (i*3+kx)*5 + c, col = 2*y0+c
    for (int q = tid; q < 30 * TPAD_ / 4; q += 256)
        ((float4*)u.sp)[q] = make_float4(0.f, 0.f, 0.f, 0.f);
    __syncthreads();
    for (int q = tid; q < 30 * 24; q += 256) {
        int row = q / 24, f4 = q % 24;
        int c = row % 5, rr = row / 5;
        int kx = rr % 3, i = rr / 3;
        int col = 2 * y0 + c;
        if (col < W_) {
            const float4* src = (const float4*)(in +
                ((((size_t)b * CI_ + i) * H_ + (2 * x + kx)) * W_ + col) * T_);
            *(float4*)(&u.sp[row][48 + f4 * 4]) = src[f4];
        }
    }
    __syncthreads();

    float mbest[5];
    int   abest[5];
#pragma unroll
    for (int j = 0; j < 5; ++j) { mbest[j] = -1e30f; abest[j] = 0; }

    int obase = __builtin_amdgcn_readfirstlane(wq * 16);

#pragma unroll 1
    for (int oi = 0; oi < 16; ++oi) {
        int o = obase + oi;
        const int* ksrow = kstab + o * NTAP_;
        float a0 = 0.f, a1 = 0.f, a2 = 0.f, a3 = 0.f, a4 = 0.f;
        int ks_next = ksrow[0];
#pragma unroll 1
        for (int tap = 0; tap < NTAP_; ++tap) {
            int ks = __builtin_amdgcn_readfirstlane(ks_next);
            if (tap + 1 < NTAP_) ks_next = ksrow[tap + 1];   // prefetch next tap
            if (ks >= 48) continue;
            int i = tap / 9, kx = (tap % 9) / 3, ky = tap % 3;
            const float* sptr = u.sp[(i * 3 + kx) * 5 + 2 * dy + ky] + t0;
            const float* wrow = wkf + (o * NTAP_ + tap) * 48;
            float w0, w1, w2, w3, w4;
            switch (ks) {
                CASE(0,  L0)  CASE(5,  L5)  CASE(10, L10) CASE(15, L15)
                CASE(20, L20) CASE(25, L25) CASE(30, L30) CASE(35, L35)
                CASE(40, L40) CASE(45, L45)
                default: goto Ldone;
            }
            L0:  SEG(0)
            L5:  SEG(5)
            L10: SEG(10)
            L15: SEG(15)
            L20: SEG(20)
            L25: SEG(25)
            L30: SEG(30)
            L35: SEG(35)
            L40: SEG(40)
            L45: {   // kt = 45, 46 (K[47] == 0 always); window w_j == s[t0+45+j]
                float k45 = wrow[45], k46 = wrow[46];
                a0 = fmaf(k45, w0, a0); a1 = fmaf(k45, w1, a1); a2 = fmaf(k45, w2, a2);
                a3 = fmaf(k45, w3, a3); a4 = fmaf(k45, w4, a4);
                float w5 = sptr[50];
                a0 = fmaf(k46, w1, a0); a1 = fmaf(k46, w2, a1); a2 = fmaf(k46, w3, a2);
                a3 = fmaf(k46, w4, a3); a4 = fmaf(k46, w5, a4);
            }
            Ldone: ;
        }
        // incremental max/argmax (strict >, o ascending => smallest o on ties)
        float bo = bias[o];
        float p0 = a0 + bo, p1 = a1 + bo, p2 = a2 + bo, p3 = a3 + bo, p4 = a4 + bo;
        if (p0 > mbest[0]) { mbest[0] = p0; abest[0] = o; }
        if (p1 > mbest[1]) { mbest[1] = p1; abest[1] = o; }
        if (p2 > mbest[2]) { mbest[2] = p2; abest[2] = o; }
        if (p3 > mbest[3]) { mbest[3] = p3; abest[3] = o; }
        if (p4 > mbest[4]) { mbest[4] = p4; abest[4] = o; }
    }

    __syncthreads();   // done reading u.sp — safe to overwrite with u.red
#pragma unroll
    for (int j = 0; j < 5; ++j) { u.red.m[wq][lane][j] = mbest[j]; u.red.a[wq][lane][j] = abest[j]; }
    __syncthreads();
    if (wq == 0 && valid) {
        int site = x * XO_ + y;
#pragma unroll
        for (int j = 0; j < 5; ++j) {
            float mv = u.red.m[0][lane][j];
            int   av = u.red.a[0][lane][j];
#pragma unroll
            for (int w = 1; w < 4; ++w) {
                float m2 = u.red.m[w][lane][j];
                if (m2 > mv) { mv = m2; av = u.red.a[w][lane][j]; }
            }
            size_t off = ((size_t)b * TP_ + (t0 + j)) * NSITE + site;
            m_out[off] = mv;
            a_out[off] = av;
        }
    }
}

// ---------------- kernel: sequential WTA ----------------
// one block per batch, 576 threads (site = tid). coalesced [b][t][site] loads,
// next-t prefetch, 1 barrier/step via double-buffered counts.
__launch_bounds__(576)
__global__ void k_wta(const float* __restrict__ m_in, const int* __restrict__ a_in,
                      float* __restrict__ out) {
    int b = blockIdx.x;
    int tid = threadIdx.x;
    int lane = tid & 63;
    int wid = tid >> 6;                 // 9 waves
    __shared__ int cnts[2][9];

    bool site = (tid < NSITE);
    const float* mb = m_in + (size_t)b * TP_ * NSITE;
    const int*   ab = a_in + (size_t)b * TP_ * NSITE;
    int dep = 0;
    float mv = site ? mb[tid] : 0.f;
    int   av = site ? ab[tid] : 0;

    for (int t = 0; t < TP_; ++t) {
        unsigned long long ball = __ballot(dep != 0);
        if (lane == 0) cnts[t & 1][wid] = __popcll(ball);
        // prefetch next row while the barrier settles
        float mv2 = 0.f; int av2 = 0;
        if (site && t + 1 < TP_) {
            mv2 = mb[(t + 1) * NSITE + tid];
            av2 = ab[(t + 1) * NSITE + tid];
        }
        __syncthreads();
        int tot = 0;
#pragma unroll
        for (int w = 0; w < 9; ++w) tot += cnts[t & 1][w];
        if (site) {
            if ((tot < WCAP_) && (dep == 0) && (mv > THETA_)) {
                out[(((size_t)b * CO_ + av) * NSITE + tid) * TP_ + t] = 1.0f;
                dep = FODEP_ - 1;
            } else {
                dep = dep ? dep - 1 : 0;
            }
        }
        mv = mv2; av = av2;
    }
}

// ---------------- launcher ----------------
extern "C" void kernel_launch(void* const* d_in, const int* in_sizes, int n_in,
                              void* d_out, int out_size, void* d_ws, size_t ws_size,
                              hipStream_t stream) {
    const float* in     = (const float*)d_in[0];
    const float* weight = (const float*)d_in[1];
    const float* bias   = (const float*)d_in[2];
    float* out = (float*)d_out;

    float* wkf   = (float*)d_ws + WS_WKF;
    int*   kstab = (int*)((float*)d_ws + WS_KS);
    float* m     = (float*)d_ws + WS_M;
    int*   a     = (int*)((float*)d_ws + WS_A);

    k_zero<<<2048, 256, 0, stream>>>((float4*)out, 19636480 / 4);
    k_wk<<<(CO_ * NTAP_ + 255) / 256, 256, 0, stream>>>(weight, wkf, kstab);
    k_conv<<<B_ * XO_ * 12, 256, 0, stream>>>(in, wkf, kstab, bias, m, a);
    k_wta<<<B_, 576, 0, stream>>>(m, a, out);
}

// Round 4
// 361.943 us; speedup vs baseline: 1.9492x; 1.2426x over previous
//
#include <hip/hip_runtime.h>

// ---------------- problem constants ----------------
#define B_    4
#define CI_   2
#define H_    48
#define W_    48
#define T_    96
#define CO_   64
#define XO_   23
#define NSITE 529         // 23*23
#define TP_   145         // output time steps (29*5)
#define TPAD_ 192         // padded LDS time window per row (max read idx 190)
#define NTAP_ 18          // CI*3*3
#define THETA_ 5.4f
#define FODEP_ 48
#define WCAP_  265        // ceil(0.5*529)
#define NOUT4 (19636480 / 4)

// ws layout (floats)
#define WS_WKF 0                      // [64][18][48] = 55296 floats
#define WS_KS  55296                  // [64][18] ints
#define WS_M   (55296 + 1152)         // [4][145][529] floats
#define WS_A   (WS_M + 306820)        // [4][145][529] ints

// ---------------- kernel: temporal kernel synthesis + start-index table ----
__global__ void k_wk(const float* __restrict__ weight, float* __restrict__ wkf,
                     int* __restrict__ kstab) {
    int idx = blockIdx.x * 256 + threadIdx.x;       // (o, tap)
    if (idx >= CO_ * NTAP_) return;
    int o = idx / NTAP_, tap = idx % NTAP_;
    int i = tap / 9, kx = (tap % 9) / 3, ky = tap % 3;
    float w = weight[((o * CI_ + i) * 3 + kx) * 3 + ky];
    int ktlo = 48;
    for (int kt = 0; kt < 48; ++kt) {
        float j = (float)(47 - kt);
        float v = fmaxf(0.0f, fminf(j * (1.0f / 16.0f), 1.5f * w - j * (1.0f / 32.0f)));
        wkf[idx * 48 + kt] = v;
        if (v > 0.0f && ktlo == 48) ktlo = kt;
    }
    kstab[idx] = (ktlo >= 48) ? 48 : (ktlo - ktlo % 5);
}

// 5-step FIR segment, 5-phase rotating register window.
// entry invariant: w_j == s[t0 + S + j]; exit: w_j == s[t0 + S + 5 + j]
#define SEG(S) \
    { float k0 = wrow[(S)+0], k1 = wrow[(S)+1], k2 = wrow[(S)+2], \
            k3 = wrow[(S)+3], k4 = wrow[(S)+4]; \
      a0 = fmaf(k0, w0, a0); a1 = fmaf(k0, w1, a1); a2 = fmaf(k0, w2, a2); \
      a3 = fmaf(k0, w3, a3); a4 = fmaf(k0, w4, a4); w0 = sptr[(S)+5]; \
      a0 = fmaf(k1, w1, a0); a1 = fmaf(k1, w2, a1); a2 = fmaf(k1, w3, a2); \
      a3 = fmaf(k1, w4, a3); a4 = fmaf(k1, w0, a4); w1 = sptr[(S)+6]; \
      a0 = fmaf(k2, w2, a0); a1 = fmaf(k2, w3, a1); a2 = fmaf(k2, w4, a2); \
      a3 = fmaf(k2, w0, a3); a4 = fmaf(k2, w1, a4); w2 = sptr[(S)+7]; \
      a0 = fmaf(k3, w3, a0); a1 = fmaf(k3, w4, a1); a2 = fmaf(k3, w0, a2); \
      a3 = fmaf(k3, w1, a3); a4 = fmaf(k3, w2, a4); w3 = sptr[(S)+8]; \
      a0 = fmaf(k4, w4, a0); a1 = fmaf(k4, w0, a1); a2 = fmaf(k4, w1, a2); \
      a3 = fmaf(k4, w2, a3); a4 = fmaf(k4, w3, a4); w4 = sptr[(S)+9]; }

// ---------------- kernel: conv + channel max/argmax (+ output zero-fill) ----
// block = (b, x, ychunk of 2). 512 threads = 8 waves; wave wq owns channels
// [8wq, 8wq+8) (wave-uniform o => scalar k loads). lane = 2dy x 32tg, t_tile=5.
__launch_bounds__(512, 8)
__global__ void k_conv(const float* __restrict__ in, const float* __restrict__ wkf,
                       const int* __restrict__ kstab, const float* __restrict__ bias,
                       float* __restrict__ m_out, int* __restrict__ a_out,
                       float4* __restrict__ out4) {
    __shared__ __align__(16) union {
        float sp[30][TPAD_];                                   // 23040 B
        struct { float m[8][64][5]; int a[8][64][5]; } red;    // 20480 B
    } u;

    int bid = blockIdx.x;
    int b  = bid / (XO_ * 12);
    int r  = bid % (XO_ * 12);
    int x  = r / 12;
    int y0 = (r % 12) * 2;
    int tid  = threadIdx.x;
    int lane = tid & 63;
    int dy   = lane >> 5;                 // 0/1
    int tg   = lane & 31;                 // t-group
    int t0   = (tg < 29) ? tg * 5 : 140;  // clamp garbage lanes in-bounds
    int y    = y0 + dy;
    bool valid = (y < XO_) && (tg < 29);

    // fold-in: zero the spike output (fire-and-forget stores, hidden by compute)
    {
        int stride = gridDim.x * blockDim.x;                   // 565248
        float4 z = make_float4(0.f, 0.f, 0.f, 0.f);
        for (int i2 = bid * blockDim.x + tid; i2 < NOUT4; i2 += stride) out4[i2] = z;
    }

    // zero pad (float4) then fill rows. row = (i*3+kx)*5 + c, col = 2*y0+c
    for (int q = tid; q < 30 * TPAD_ / 4; q += 512)
        ((float4*)u.sp)[q] = make_float4(0.f, 0.f, 0.f, 0.f);
    __syncthreads();
    for (int q = tid; q < 30 * 24; q += 512) {
        int row = q / 24, f4 = q % 24;
        int c = row % 5, rr = row / 5;
        int kx = rr % 3, i = rr / 3;
        int col = 2 * y0 + c;
        if (col < W_) {
            const float4* src = (const float4*)(in +
                ((((size_t)b * CI_ + i) * H_ + (2 * x + kx)) * W_ + col) * T_);
            *(float4*)(&u.sp[row][48 + f4 * 4]) = src[f4];
        }
    }
    __syncthreads();

    float mbest[5];
    int   abest[5];
#pragma unroll
    for (int j = 0; j < 5; ++j) { mbest[j] = -1e30f; abest[j] = 0; }

    int wq    = __builtin_amdgcn_readfirstlane(tid >> 6);
    int obase = wq * 8;

#pragma unroll 1
    for (int oi = 0; oi < 8; ++oi) {
        int o = obase + oi;
        const int* ksrow = kstab + o * NTAP_;
        float a0 = 0.f, a1 = 0.f, a2 = 0.f, a3 = 0.f, a4 = 0.f;
        int ks_next = ksrow[0];
#pragma unroll 1
        for (int tap = 0; tap < NTAP_; ++tap) {
            int ks = __builtin_amdgcn_readfirstlane(ks_next);
            if (tap + 1 < NTAP_) ks_next = ksrow[tap + 1];   // prefetch next tap
            if (ks >= 48) continue;
            int i = tap / 9, kx = (tap % 9) / 3, ky = tap % 3;
            const float* sptr = u.sp[(i * 3 + kx) * 5 + 2 * dy + ky] + t0;
            const float* wrow = wkf + (o * NTAP_ + tap) * 48;
            // load window at (uniform) ks; guarded straight-line segment chain
            float w0 = sptr[ks], w1 = sptr[ks + 1], w2 = sptr[ks + 2],
                  w3 = sptr[ks + 3], w4 = sptr[ks + 4];
            if (ks <= 0)  SEG(0)
            if (ks <= 5)  SEG(5)
            if (ks <= 10) SEG(10)
            if (ks <= 15) SEG(15)
            if (ks <= 20) SEG(20)
            if (ks <= 25) SEG(25)
            if (ks <= 30) SEG(30)
            if (ks <= 35) SEG(35)
            if (ks <= 40) SEG(40)
            {   // tail kt = 45, 46 (K[47] == 0 always); entry w_j == s[t0+45+j]
                float k45 = wrow[45], k46 = wrow[46];
                a0 = fmaf(k45, w0, a0); a1 = fmaf(k45, w1, a1); a2 = fmaf(k45, w2, a2);
                a3 = fmaf(k45, w3, a3); a4 = fmaf(k45, w4, a4);
                float w5 = sptr[50];
                a0 = fmaf(k46, w1, a0); a1 = fmaf(k46, w2, a1); a2 = fmaf(k46, w3, a2);
                a3 = fmaf(k46, w4, a3); a4 = fmaf(k46, w5, a4);
            }
        }
        // incremental max/argmax (strict >, o ascending => smallest o on ties)
        float bo = bias[o];
        float p0 = a0 + bo, p1 = a1 + bo, p2 = a2 + bo, p3 = a3 + bo, p4 = a4 + bo;
        if (p0 > mbest[0]) { mbest[0] = p0; abest[0] = o; }
        if (p1 > mbest[1]) { mbest[1] = p1; abest[1] = o; }
        if (p2 > mbest[2]) { mbest[2] = p2; abest[2] = o; }
        if (p3 > mbest[3]) { mbest[3] = p3; abest[3] = o; }
        if (p4 > mbest[4]) { mbest[4] = p4; abest[4] = o; }
    }

    __syncthreads();   // done reading u.sp — safe to overwrite with u.red
#pragma unroll
    for (int j = 0; j < 5; ++j) { u.red.m[wq][lane][j] = mbest[j]; u.red.a[wq][lane][j] = abest[j]; }
    __syncthreads();
    if (wq == 0 && valid) {
        int site = x * XO_ + y;
#pragma unroll
        for (int j = 0; j < 5; ++j) {
            float mv = u.red.m[0][lane][j];
            int   av = u.red.a[0][lane][j];
#pragma unroll
            for (int w = 1; w < 8; ++w) {
                float m2 = u.red.m[w][lane][j];
                if (m2 > mv) { mv = m2; av = u.red.a[w][lane][j]; }
            }
            size_t off = ((size_t)b * TP_ + (t0 + j)) * NSITE + site;
            m_out[off] = mv;
            a_out[off] = av;
        }
    }
}

// ---------------- kernel: sequential WTA ----------------
// one block per batch, 576 threads (site = tid). coalesced [b][t][site] loads,
// next-t prefetch, 1 barrier/step via double-buffered counts.
__launch_bounds__(576)
__global__ void k_wta(const float* __restrict__ m_in, const int* __restrict__ a_in,
                      float* __restrict__ out) {
    int b = blockIdx.x;
    int tid = threadIdx.x;
    int lane = tid & 63;
    int wid = tid >> 6;                 // 9 waves
    __shared__ int cnts[2][9];

    bool site = (tid < NSITE);
    const float* mb = m_in + (size_t)b * TP_ * NSITE;
    const int*   ab = a_in + (size_t)b * TP_ * NSITE;
    int dep = 0;
    float mv = site ? mb[tid] : 0.f;
    int   av = site ? ab[tid] : 0;

    for (int t = 0; t < TP_; ++t) {
        unsigned long long ball = __ballot(dep != 0);
        if (lane == 0) cnts[t & 1][wid] = __popcll(ball);
        // prefetch next row while the barrier settles
        float mv2 = 0.f; int av2 = 0;
        if (site && t + 1 < TP_) {
            mv2 = mb[(t + 1) * NSITE + tid];
            av2 = ab[(t + 1) * NSITE + tid];
        }
        __syncthreads();
        int tot = 0;
#pragma unroll
        for (int w = 0; w < 9; ++w) tot += cnts[t & 1][w];
        if (site) {
            if ((tot < WCAP_) && (dep == 0) && (mv > THETA_)) {
                out[(((size_t)b * CO_ + av) * NSITE + tid) * TP_ + t] = 1.0f;
                dep = FODEP_ - 1;
            } else {
                dep = dep ? dep - 1 : 0;
            }
        }
        mv = mv2; av = av2;
    }
}

// ---------------- launcher ----------------
extern "C" void kernel_launch(void* const* d_in, const int* in_sizes, int n_in,
                              void* d_out, int out_size, void* d_ws, size_t ws_size,
                              hipStream_t stream) {
    const float* in     = (const float*)d_in[0];
    const float* weight = (const float*)d_in[1];
    const float* bias   = (const float*)d_in[2];
    float* out = (float*)d_out;

    float* wkf   = (float*)d_ws + WS_WKF;
    int*   kstab = (int*)((float*)d_ws + WS_KS);
    float* m     = (float*)d_ws + WS_M;
    int*   a     = (int*)((float*)d_ws + WS_A);

    k_wk<<<(CO_ * NTAP_ + 255) / 256, 256, 0, stream>>>(weight, wkf, kstab);
    k_conv<<<B_ * XO_ * 12, 512, 0, stream>>>(in, wkf, kstab, bias, m, a, (float4*)out);
    k_wta<<<B_, 576, 0, stream>>>(m, a, out);
}